// Round 2
// baseline (250.494 us; speedup 1.0000x reference)
//
#include <hip/hip_runtime.h>
#include <math.h>

#define NN 2048   // nodes
#define IF 128    // in features
#define NH 4      // heads
#define NF 16     // hidden per head
#define OF 64     // NH*NF
#define NTILE (NN / 64)   // 32 j-tiles of 64

__device__ __forceinline__ float rfl(float x) {   // force wave-uniform value into SGPR
    return __int_as_float(__builtin_amdgcn_readfirstlane(__float_as_int(x)));
}

// ---------------- Kernel 1: projections + attention-bias precompute ----------------
// grid NN/2, block 256 (4 waves). wave w -> node (blockIdx.x*2 + (w>>1)), matrix (w&1).
// Writes g_l, g_r [NN][OF], and cj6[h][j] = 0.6*sum_f aw_f*g_l[j,h,f], bi6[h][i] likewise from g_r.
__global__ __launch_bounds__(256) void proj_kernel(const float* __restrict__ h,
                                                   const float* __restrict__ Wl,
                                                   const float* __restrict__ Wr,
                                                   const float* __restrict__ attn_w,
                                                   float* __restrict__ gl,
                                                   float* __restrict__ gr,
                                                   float* __restrict__ cj6,
                                                   float* __restrict__ bi6) {
    const int t    = threadIdx.x;
    const int w    = t >> 6, lane = t & 63;
    const int il   = w >> 1, which = w & 1;          // which: 0 = W_l, 1 = W_r
    const int i    = blockIdx.x * 2 + il;

    __shared__ float hs[2][IF];
    hs[t >> 7][t & 127] = h[(blockIdx.x * 2 + (t >> 7)) * IF + (t & 127)];
    __syncthreads();

    const float* W = which ? Wr : Wl;
    float acc = 0.f;
    #pragma unroll
    for (int k = 0; k < IF; ++k)
        acc = fmaf(hs[il][k], W[k * OF + lane], acc);   // coalesced W read per wave

    float* g = which ? gr : gl;
    g[i * OF + lane] = acc;

    // per-head dot with attn_w: reduce within each 16-lane head group
    float v = acc * attn_w[lane & 15];
    v += __shfl_xor(v, 1);
    v += __shfl_xor(v, 2);
    v += __shfl_xor(v, 4);
    v += __shfl_xor(v, 8);
    if ((lane & 15) == 0) {
        float* dst = which ? bi6 : cj6;
        dst[(lane >> 4) * NN + i] = 0.6f * v;
    }
}

// ---------------- Kernel 2: fused flash-style GAT ----------------
// grid NN/4, block 1024 (16 waves). wave wid -> head (wid&3), node i = bx*4 + (wid>>2).
// lane = j within tile; per-lane online softmax (m,l,acc[16]); merge across lanes at end.
__global__ __launch_bounds__(1024) void gat_kernel(const float* __restrict__ g_l,
                                                   const float* __restrict__ g_r,
                                                   const float* __restrict__ cj6,
                                                   const float* __restrict__ bi6,
                                                   const int*   __restrict__ adj,
                                                   const float* __restrict__ attn_w,
                                                   float*       __restrict__ out) {
    const int t    = threadIdx.x;
    const int wid  = t >> 6, lane = t & 63;
    const int h    = wid & 3;
    const int i    = blockIdx.x * 4 + (wid >> 2);

    // wave-uniform values -> SGPR
    float aw_s[NF], gr_s[NF];
    #pragma unroll
    for (int f = 0; f < NF; ++f) {
        aw_s[f] = rfl(attn_w[f]);
        gr_s[f] = rfl(g_r[i * OF + h * NF + f]);
    }
    const float bi = rfl(bi6[h * NN + i]);

    const float* glh = g_l + h * NF;     // + j*OF gives this head's 16-float slice of row j
    const float* grh = g_r + h * NF;
    const float* cjh = cj6 + h * NN;
    const int*   arw = adj + (size_t)i * NN;

    float m = -INFINITY, l = 0.f;
    float acc[NF];
    #pragma unroll
    for (int f = 0; f < NF; ++f) acc[f] = 0.f;

    float4 gA[4], rA[4], gB[4], rB[4];
    float  cjA, cjB;
    int    adA, adB;

#define LOADT(tt, gg, rr, cj, ad)                                          \
    {                                                                      \
        const int j = (tt) * 64 + lane;                                    \
        const float4* pg = (const float4*)(glh + (size_t)j * OF);          \
        const float4* pr = (const float4*)(grh + (size_t)j * OF);          \
        gg[0] = pg[0]; gg[1] = pg[1]; gg[2] = pg[2]; gg[3] = pg[3];        \
        rr[0] = pr[0]; rr[1] = pr[1]; rr[2] = pr[2]; rr[3] = pr[3];        \
        cj = cjh[j]; ad = arw[j];                                          \
    }

#define STEPT(gg, rr, cj, ad)                                              \
    {                                                                      \
        float s = 0.f;                                                     \
        _Pragma("unroll")                                                  \
        for (int q = 0; q < 4; ++q) {                                      \
            const float4 v = gg[q];                                        \
            s = fmaf(fabsf(v.x + gr_s[q * 4 + 0]), aw_s[q * 4 + 0], s);    \
            s = fmaf(fabsf(v.y + gr_s[q * 4 + 1]), aw_s[q * 4 + 1], s);    \
            s = fmaf(fabsf(v.z + gr_s[q * 4 + 2]), aw_s[q * 4 + 2], s);    \
            s = fmaf(fabsf(v.w + gr_s[q * 4 + 3]), aw_s[q * 4 + 3], s);    \
        }                                                                  \
        const float e = fmaf(0.4f, s, bi + cj);                            \
        const bool msk = (ad != 0);                                        \
        const float ee = msk ? e : -INFINITY;                              \
        if (__any(ee > m + 8.f)) {            /* rare: deferred rescale */ \
            const bool  c     = ee > m + 8.f;                              \
            const float alpha = c ? __expf(m - ee) : 1.f;                  \
            m = c ? ee : m;                                                \
            l *= alpha;                                                    \
            _Pragma("unroll")                                              \
            for (int f = 0; f < NF; ++f) acc[f] *= alpha;                  \
        }                                                                  \
        const float p = msk ? __expf(e - m) : 0.f;                         \
        l += p;                                                            \
        _Pragma("unroll")                                                  \
        for (int q = 0; q < 4; ++q) {                                      \
            const float4 v = rr[q];                                        \
            acc[q * 4 + 0] = fmaf(p, v.x, acc[q * 4 + 0]);                 \
            acc[q * 4 + 1] = fmaf(p, v.y, acc[q * 4 + 1]);                 \
            acc[q * 4 + 2] = fmaf(p, v.z, acc[q * 4 + 2]);                 \
            acc[q * 4 + 3] = fmaf(p, v.w, acc[q * 4 + 3]);                 \
        }                                                                  \
    }

    // ping-pong double buffer over 32 tiles
    LOADT(0, gA, rA, cjA, adA);
    for (int tt = 0; tt < NTILE; tt += 2) {
        LOADT(tt + 1, gB, rB, cjB, adB);
        STEPT(gA, rA, cjA, adA);
        const int nx = (tt + 2 < NTILE) ? tt + 2 : NTILE - 1;  // clamped redundant load on last iter
        LOADT(nx, gA, rA, cjA, adA);
        STEPT(gB, rB, cjB, adB);
    }
#undef LOADT
#undef STEPT

    // ---- merge (m, l, acc) across the 64 lanes ----
    float M = m;
    #pragma unroll
    for (int off = 32; off; off >>= 1) M = fmaxf(M, __shfl_xor(M, off));
    const float sc = (m > -INFINITY) ? __expf(m - M) : 0.f;   // 0 for never-initialized lanes
    l *= sc;
    #pragma unroll
    for (int off = 32; off; off >>= 1) l += __shfl_xor(l, off);

    #pragma unroll
    for (int f = 0; f < NF; ++f) {
        float a = acc[f] * sc;
        a += __shfl_xor(a, 32);
        a += __shfl_xor(a, 16);
        acc[f] = a;      // lanes r, r+16, r+32, r+48 now hold identical group sums
    }

    __shared__ float red[16][16][NF + 1];
    if (lane < 16) {
        #pragma unroll
        for (int f = 0; f < NF; ++f) red[wid][lane][f] = acc[f];
    }
    __syncthreads();
    if (lane < NF) {
        float s = 0.f;
        #pragma unroll
        for (int r = 0; r < 16; ++r) s += red[wid][r][lane];
        out[i * OF + h * NF + lane] = (l > 0.f) ? s / l : 0.f;   // l==0 -> nan_to_num(0)
    }
}

extern "C" void kernel_launch(void* const* d_in, const int* in_sizes, int n_in,
                              void* d_out, int out_size, void* d_ws, size_t ws_size,
                              hipStream_t stream) {
    const float* h      = (const float*)d_in[0];
    const int*   adj    = (const int*)d_in[1];
    const float* W_l    = (const float*)d_in[2];
    const float* W_r    = (const float*)d_in[3];
    const float* attn_w = (const float*)d_in[4];
    float*       out    = (float*)d_out;

    float* g_l = (float*)d_ws;                    // [NN][OF]
    float* g_r = g_l + (size_t)NN * OF;           // [NN][OF]
    float* cj6 = g_r + (size_t)NN * OF;           // [NH][NN]
    float* bi6 = cj6 + (size_t)NH * NN;           // [NH][NN]

    proj_kernel<<<NN / 2, 256, 0, stream>>>(h, W_l, W_r, attn_w, g_l, g_r, cj6, bi6);
    gat_kernel<<<NN / 4, 1024, 0, stream>>>(g_l, g_r, cj6, bi6, adj, attn_w, out);
}

// Round 3
// 141.237 us; speedup vs baseline: 1.7736x; 1.7736x over previous
//
#include <hip/hip_runtime.h>
#include <math.h>

#define NN 2048   // nodes
#define IF 128    // in features
#define NH 4      // heads
#define NF 16     // hidden per head
#define OF 64     // NH*NF
#define NTILE (NN / 64)   // 32 j-tiles of 64

__device__ __forceinline__ float rfl(float x) {   // force wave-uniform value into SGPR
    return __int_as_float(__builtin_amdgcn_readfirstlane(__float_as_int(x)));
}

// ---------------- Kernel 1: projections (head-major) + attention-bias precompute ----------------
// grid NN/2, block 256 (4 waves). wave w -> node (blockIdx.x*2 + (w>>1)), matrix (w&1).
// Writes glt/grt [NH][NN][NF] (head-major!), and cj6[h][j] = 0.6*sum_f aw_f*glt[h,j,f],
// bi6[h][i] likewise from grt.
__global__ __launch_bounds__(256) void proj_kernel(const float* __restrict__ h,
                                                   const float* __restrict__ Wl,
                                                   const float* __restrict__ Wr,
                                                   const float* __restrict__ attn_w,
                                                   float* __restrict__ glt,
                                                   float* __restrict__ grt,
                                                   float* __restrict__ cj6,
                                                   float* __restrict__ bi6) {
    const int t    = threadIdx.x;
    const int w    = t >> 6, lane = t & 63;
    const int il   = w >> 1, which = w & 1;          // which: 0 = W_l, 1 = W_r
    const int i    = blockIdx.x * 2 + il;

    __shared__ float hs[2][IF];
    hs[t >> 7][t & 127] = h[(blockIdx.x * 2 + (t >> 7)) * IF + (t & 127)];
    __syncthreads();

    const float* W = which ? Wr : Wl;
    float acc = 0.f;
    #pragma unroll
    for (int k = 0; k < IF; ++k)
        acc = fmaf(hs[il][k], W[k * OF + lane], acc);   // coalesced W read per wave

    // head-major write: g[h][i][f], lane = h*16+f -> 4 x 64B segments per wave
    float* g = which ? grt : glt;
    g[(lane >> 4) * (NN * NF) + i * NF + (lane & 15)] = acc;

    // per-head dot with attn_w: reduce within each 16-lane head group
    float v = acc * attn_w[lane & 15];
    v += __shfl_xor(v, 1);
    v += __shfl_xor(v, 2);
    v += __shfl_xor(v, 4);
    v += __shfl_xor(v, 8);
    if ((lane & 15) == 0) {
        float* dst = which ? bi6 : cj6;
        dst[(lane >> 4) * NN + i] = 0.6f * v;
    }
}

// ---------------- Kernel 2: fused flash-style GAT ----------------
// grid NN/4, block 1024 (16 waves). wave wid -> head (wid&3), node i = bx*4 + (wid>>2).
// lane = j within tile; per-lane online softmax (m,l,acc[16]); merge across lanes at end.
__global__ __launch_bounds__(1024) void gat_kernel(const float* __restrict__ glt,
                                                   const float* __restrict__ grt,
                                                   const float* __restrict__ cj6,
                                                   const float* __restrict__ bi6,
                                                   const int*   __restrict__ adj,
                                                   const float* __restrict__ attn_w,
                                                   float*       __restrict__ out) {
    const int t    = threadIdx.x;
    const int wid  = t >> 6, lane = t & 63;
    const int h    = wid & 3;
    const int i    = blockIdx.x * 4 + (wid >> 2);

    // wave-uniform values -> SGPR
    float aw_s[NF], gr_s[NF];
    #pragma unroll
    for (int f = 0; f < NF; ++f) {
        aw_s[f] = rfl(attn_w[f]);
        gr_s[f] = rfl(grt[h * (NN * NF) + i * NF + f]);   // broadcast load
    }
    const float bi = rfl(bi6[h * NN + i]);

    const float* glh = glt + (size_t)h * NN * NF;   // + j*16: per-lane CONTIGUOUS 64B
    const float* grh = grt + (size_t)h * NN * NF;
    const float* cjh = cj6 + h * NN;
    const int*   arw = adj + (size_t)i * NN;

    float m = -INFINITY, l = 0.f;
    float acc[NF];
    #pragma unroll
    for (int f = 0; f < NF; ++f) acc[f] = 0.f;

    float4 gA[4], rA[4], gB[4], rB[4];
    float  cjA, cjB;
    int    adA, adB;

#define LOADT(tt, gg, rr, cj, ad)                                          \
    {                                                                      \
        const int j = (tt) * 64 + lane;                                    \
        const float4* pg = (const float4*)(glh + (size_t)j * NF);          \
        const float4* pr = (const float4*)(grh + (size_t)j * NF);          \
        gg[0] = pg[0]; gg[1] = pg[1]; gg[2] = pg[2]; gg[3] = pg[3];        \
        rr[0] = pr[0]; rr[1] = pr[1]; rr[2] = pr[2]; rr[3] = pr[3];        \
        cj = cjh[j]; ad = arw[j];                                          \
    }

#define STEPT(gg, rr, cj, ad)                                              \
    {                                                                      \
        float s = 0.f;                                                     \
        _Pragma("unroll")                                                  \
        for (int q = 0; q < 4; ++q) {                                      \
            const float4 v = gg[q];                                        \
            s = fmaf(fabsf(v.x + gr_s[q * 4 + 0]), aw_s[q * 4 + 0], s);    \
            s = fmaf(fabsf(v.y + gr_s[q * 4 + 1]), aw_s[q * 4 + 1], s);    \
            s = fmaf(fabsf(v.z + gr_s[q * 4 + 2]), aw_s[q * 4 + 2], s);    \
            s = fmaf(fabsf(v.w + gr_s[q * 4 + 3]), aw_s[q * 4 + 3], s);    \
        }                                                                  \
        const float e = fmaf(0.4f, s, bi + cj);                            \
        const bool msk = (ad != 0);                                        \
        const float ee = msk ? e : -INFINITY;                              \
        if (__any(ee > m + 8.f)) {            /* rare: deferred rescale */ \
            const bool  c     = ee > m + 8.f;                              \
            const float alpha = c ? __expf(m - ee) : 1.f;                  \
            m = c ? ee : m;                                                \
            l *= alpha;                                                    \
            _Pragma("unroll")                                              \
            for (int f = 0; f < NF; ++f) acc[f] *= alpha;                  \
        }                                                                  \
        const float p = msk ? __expf(e - m) : 0.f;                         \
        l += p;                                                            \
        _Pragma("unroll")                                                  \
        for (int q = 0; q < 4; ++q) {                                      \
            const float4 v = rr[q];                                        \
            acc[q * 4 + 0] = fmaf(p, v.x, acc[q * 4 + 0]);                 \
            acc[q * 4 + 1] = fmaf(p, v.y, acc[q * 4 + 1]);                 \
            acc[q * 4 + 2] = fmaf(p, v.z, acc[q * 4 + 2]);                 \
            acc[q * 4 + 3] = fmaf(p, v.w, acc[q * 4 + 3]);                 \
        }                                                                  \
    }

    // ping-pong double buffer over 32 tiles; raw barrier (no waitcnt drain)
    // keeps the 16 waves loosely converged for adj-row L1/L2 locality.
    LOADT(0, gA, rA, cjA, adA);
    for (int tt = 0; tt < NTILE; tt += 2) {
        __builtin_amdgcn_s_barrier();
        LOADT(tt + 1, gB, rB, cjB, adB);
        STEPT(gA, rA, cjA, adA);
        const int nx = (tt + 2 < NTILE) ? tt + 2 : NTILE - 1;  // clamped redundant load on last iter
        LOADT(nx, gA, rA, cjA, adA);
        STEPT(gB, rB, cjB, adB);
    }
#undef LOADT
#undef STEPT

    // ---- merge (m, l, acc) across the 64 lanes ----
    float M = m;
    #pragma unroll
    for (int off = 32; off; off >>= 1) M = fmaxf(M, __shfl_xor(M, off));
    const float sc = (m > -INFINITY) ? __expf(m - M) : 0.f;   // 0 for never-initialized lanes
    l *= sc;
    #pragma unroll
    for (int off = 32; off; off >>= 1) l += __shfl_xor(l, off);

    #pragma unroll
    for (int f = 0; f < NF; ++f) {
        float a = acc[f] * sc;
        a += __shfl_xor(a, 32);
        a += __shfl_xor(a, 16);
        acc[f] = a;      // lanes r, r+16, r+32, r+48 now hold identical group sums
    }

    __shared__ float red[16][16][NF + 1];
    if (lane < 16) {
        #pragma unroll
        for (int f = 0; f < NF; ++f) red[wid][lane][f] = acc[f];
    }
    __syncthreads();
    if (lane < NF) {
        float s = 0.f;
        #pragma unroll
        for (int r = 0; r < 16; ++r) s += red[wid][r][lane];
        out[i * OF + h * NF + lane] = (l > 0.f) ? s / l : 0.f;   // l==0 -> nan_to_num(0)
    }
}

extern "C" void kernel_launch(void* const* d_in, const int* in_sizes, int n_in,
                              void* d_out, int out_size, void* d_ws, size_t ws_size,
                              hipStream_t stream) {
    const float* h      = (const float*)d_in[0];
    const int*   adj    = (const int*)d_in[1];
    const float* W_l    = (const float*)d_in[2];
    const float* W_r    = (const float*)d_in[3];
    const float* attn_w = (const float*)d_in[4];
    float*       out    = (float*)d_out;

    float* glt = (float*)d_ws;                    // [NH][NN][NF]
    float* grt = glt + (size_t)NN * OF;           // [NH][NN][NF]
    float* cj6 = grt + (size_t)NN * OF;           // [NH][NN]
    float* bi6 = cj6 + (size_t)NH * NN;           // [NH][NN]

    proj_kernel<<<NN / 2, 256, 0, stream>>>(h, W_l, W_r, attn_w, glt, grt, cj6, bi6);
    gat_kernel<<<NN / 4, 1024, 0, stream>>>(glt, grt, cj6, bi6, adj, attn_w, out);
}